// Round 3
// baseline (600.388 us; speedup 1.0000x reference)
//
#include <hip/hip_runtime.h>

#define N_NODES 100000
#define N_EDGES 3200000
#define F_IN 512
#define HIDDEN 16
#define N_LABELS 64

#define BW 128
#define NBUCK ((N_NODES + BW - 1) / BW)     // 782
#define NCB 256
#define SCAN_N (NBUCK * NCB)                // 200192
#define SCAN_BLKS ((SCAN_N + 1023) / 1024)  // 196
#define CAP 10240                           // LDS staging entries (40KB); buckets are 4096 +/- 64

__global__ __launch_bounds__(256) void count_kernel(
        const int* __restrict__ es, const int* __restrict__ ed,
        int* __restrict__ Msrc, int* __restrict__ Mdst) {
    __shared__ int h1[NBUCK], h2[NBUCK];
    const int tid = threadIdx.x, g = blockIdx.x;
    for (int i = tid; i < NBUCK; i += 256) { h1[i] = 0; h2[i] = 0; }
    __syncthreads();
    for (int i = g * 256 + tid; i < N_EDGES; i += NCB * 256) {
        atomicAdd(&h1[es[i] >> 7], 1);
        atomicAdd(&h2[ed[i] >> 7], 1);
    }
    __syncthreads();
    for (int i = tid; i < NBUCK; i += 256) {
        Msrc[i * NCB + g] = h1[i];
        Mdst[i * NCB + g] = h2[i];
    }
}

__global__ __launch_bounds__(256) void scanA_kernel(int* __restrict__ a, int* __restrict__ bsum) {
    __shared__ int s[256];
    const int tid = threadIdx.x;
    const int base = blockIdx.x * 1024 + tid * 4;
    int4 v = make_int4(0, 0, 0, 0);
    if (base + 3 < SCAN_N) v = *(const int4*)(a + base);
    else {
        if (base + 0 < SCAN_N) v.x = a[base + 0];
        if (base + 1 < SCAN_N) v.y = a[base + 1];
        if (base + 2 < SCAN_N) v.z = a[base + 2];
        if (base + 3 < SCAN_N) v.w = a[base + 3];
    }
    const int lsum = v.x + v.y + v.z + v.w;
    s[tid] = lsum;
    __syncthreads();
    for (int off = 1; off < 256; off <<= 1) {
        int t = (tid >= off) ? s[tid - off] : 0;
        __syncthreads();
        s[tid] += t;
        __syncthreads();
    }
    int e0 = s[tid] - lsum;
    int e1 = e0 + v.x, e2 = e1 + v.y, e3 = e2 + v.z;
    if (base + 3 < SCAN_N) *(int4*)(a + base) = make_int4(e0, e1, e2, e3);
    else {
        if (base + 0 < SCAN_N) a[base + 0] = e0;
        if (base + 1 < SCAN_N) a[base + 1] = e1;
        if (base + 2 < SCAN_N) a[base + 2] = e2;
        if (base + 3 < SCAN_N) a[base + 3] = e3;
    }
    if (tid == 255) bsum[blockIdx.x] = s[255];
}

__global__ void scanB_kernel(int* __restrict__ bsum) {
    __shared__ int s[256];
    const int tid = threadIdx.x;
    int v = (tid < SCAN_BLKS) ? bsum[tid] : 0;
    s[tid] = v;
    __syncthreads();
    for (int off = 1; off < 256; off <<= 1) {
        int t = (tid >= off) ? s[tid - off] : 0;
        __syncthreads();
        s[tid] += t;
        __syncthreads();
    }
    if (tid < SCAN_BLKS) bsum[tid] = s[tid] - v;
}

__global__ __launch_bounds__(256) void scanC_kernel(int* __restrict__ a, const int* __restrict__ bsum) {
    const int base = blockIdx.x * 1024 + threadIdx.x * 4;
    const int b = bsum[blockIdx.x];
    if (base + 3 < SCAN_N) {
        int4 v = *(int4*)(a + base);
        v.x += b; v.y += b; v.z += b; v.w += b;
        *(int4*)(a + base) = v;
    } else {
        for (int j = 0; j < 4; ++j) if (base + j < SCAN_N) a[base + j] += b;
    }
}

__global__ __launch_bounds__(256) void scatter_kernel(
        const int* __restrict__ es, const int* __restrict__ ed,
        const int* __restrict__ Ssrc, const int* __restrict__ Sdst,
        unsigned* __restrict__ pairs, unsigned char* __restrict__ srcb) {
    __shared__ int c1[NBUCK], c2[NBUCK];
    const int tid = threadIdx.x, g = blockIdx.x;
    for (int i = tid; i < NBUCK; i += 256) {
        c1[i] = Ssrc[i * NCB + g];
        c2[i] = Sdst[i * NCB + g];
    }
    __syncthreads();
    for (int i = g * 256 + tid; i < N_EDGES; i += NCB * 256) {
        int s = es[i], d = ed[i];
        int p2 = atomicAdd(&c2[d >> 7], 1);
        pairs[p2] = ((unsigned)(d & 127) << 17) | (unsigned)s;
        int p1 = atomicAdd(&c1[s >> 7], 1);
        srcb[p1] = (unsigned char)(s & 127);
    }
}

// Per-dst-bucket fine sort; converts pairs -> col IN PLACE.
__global__ __launch_bounds__(256) void csr_kernel(
        const int* __restrict__ Sdst, unsigned* __restrict__ pairs,
        int* __restrict__ row_ptr, float* __restrict__ norm_dst) {
    __shared__ unsigned buf[CAP];
    __shared__ int hist[BW], scn[BW], cur[BW];
    const int b = blockIdx.x, tid = threadIdx.x;
    const int base  = Sdst[b * NCB];
    const int nextb = (b == NBUCK - 1) ? N_EDGES : Sdst[(b + 1) * NCB];
    const int nb = nextb - base;
    const bool fits = (nb <= CAP);   // always true for this input (+96 sigma)
    if (tid < BW) hist[tid] = 0;
    __syncthreads();
    for (int i = tid; i < nb; i += 256) {
        unsigned pk = pairs[base + i];
        if (fits) buf[i] = pk;
        atomicAdd(&hist[pk >> 17], 1);
    }
    __syncthreads();
    if (tid < BW) scn[tid] = hist[tid];
    __syncthreads();
    for (int off = 1; off < BW; off <<= 1) {
        int t = 0;
        if (tid < BW && tid >= off) t = scn[tid - off];
        __syncthreads();
        if (tid < BW) scn[tid] += t;
        __syncthreads();
    }
    if (tid < BW) {
        int e = scn[tid] - hist[tid];
        cur[tid] = e;
        int node = b * BW + tid;
        if (node <= N_NODES) row_ptr[node] = base + e;
        if (node < N_NODES) norm_dst[node] = rsqrtf(fmaxf((float)hist[tid], 1.0f));
    }
    __syncthreads();
    if (fits) {
        for (int i = tid; i < nb; i += 256) {
            unsigned pk = buf[i];
            int pos = atomicAdd(&cur[pk >> 17], 1);
            pairs[base + pos] = pk & 0x1FFFFu;   // col value, within-bucket perm
        }
    } else {
        for (int i = tid; i < nb; i += 256)
            pairs[base + i] &= 0x1FFFFu;
    }
}

__global__ __launch_bounds__(256) void srcdeg_kernel(
        const int* __restrict__ Ssrc, const unsigned char* __restrict__ srcb,
        float* __restrict__ norm_src) {
    __shared__ int hist[BW];
    const int b = blockIdx.x, tid = threadIdx.x;
    const int base  = Ssrc[b * NCB];
    const int nextb = (b == NBUCK - 1) ? N_EDGES : Ssrc[(b + 1) * NCB];
    const int nb = nextb - base;
    if (tid < BW) hist[tid] = 0;
    __syncthreads();
    for (int i = tid; i < nb; i += 256)
        atomicAdd(&hist[srcb[base + i]], 1);
    __syncthreads();
    if (tid < BW) {
        int node = b * BW + tid;
        if (node < N_NODES) norm_src[node] = rsqrtf(fmaxf((float)hist[tid], 1.0f));
    }
}

// r7: remove the X->LDS staging pipeline entirely. r6's structure paid
// 3 B/FMA of LDS-read traffic (2.46GB ~ 36us > the 33us HBM floor) plus 16
// scalar ds_write_b32 per thread per chunk plus a vmcnt(0)+2-barrier drain
// every chunk (the latency serializer). New structure: thread owns 4 rows x
// 4 outs; X read directly from global as float4 (4 lanes per row share the
// address -> broadcast-coalesced; L1 absorbs line granularity, per-wave
// working set ~1KB). Only wave-uniform W1 (16KB half) lives in LDS, loaded
// once, read via 4-distinct-address broadcast ds_read_b128 (conflict-free,
// 1 B/FMA = 0.82GB total). No barriers in the main loop.
#define MM_NODES 128
#define KSPLIT 2
#define KH (F_IN / KSPLIT)   // 256 k per z-half

__global__ __launch_bounds__(128, 4) void proj1_kernel(
        const float* __restrict__ X, const float* __restrict__ W1,
        float* __restrict__ P0, float* __restrict__ P1) {
    __shared__ float w1c[KH][HIDDEN];   // 16 KB

    const int tid = threadIdx.x;
    const int node0 = blockIdx.x * MM_NODES;
    const int z = blockIdx.y;

    // stage W1 half once: 4096 floats = 1024 float4
    for (int i = tid; i < KH * HIDDEN / 4; i += 128)
        ((float4*)&w1c[0][0])[i] = ((const float4*)(W1 + (size_t)z * KH * HIDDEN))[i];
    __syncthreads();

    const int rg = tid >> 2;          // 0..31 -> rows rg*4 .. rg*4+3
    const int kq = (tid & 3) * 4;     // output quad

    const float* xr[4];
    int gn[4];
#pragma unroll
    for (int a = 0; a < 4; ++a) {
        int r = node0 + rg * 4 + a;
        gn[a] = r;
        if (r > N_NODES - 1) r = N_NODES - 1;   // clamp loads; write is guarded
        xr[a] = X + (size_t)r * F_IN + (size_t)z * KH;
    }

    float acc[4][4];
#pragma unroll
    for (int a = 0; a < 4; ++a)
#pragma unroll
        for (int b = 0; b < 4; ++b) acc[a][b] = 0.f;

    for (int c = 0; c < KH; c += 4) {
        float4 xv0 = *((const float4*)(xr[0] + c));
        float4 xv1 = *((const float4*)(xr[1] + c));
        float4 xv2 = *((const float4*)(xr[2] + c));
        float4 xv3 = *((const float4*)(xr[3] + c));
        float4 w0 = *((const float4*)&w1c[c + 0][kq]);
        float4 w1 = *((const float4*)&w1c[c + 1][kq]);
        float4 w2 = *((const float4*)&w1c[c + 2][kq]);
        float4 w3 = *((const float4*)&w1c[c + 3][kq]);

        float xv[4][4];
        xv[0][0] = xv0.x; xv[0][1] = xv0.y; xv[0][2] = xv0.z; xv[0][3] = xv0.w;
        xv[1][0] = xv1.x; xv[1][1] = xv1.y; xv[1][2] = xv1.z; xv[1][3] = xv1.w;
        xv[2][0] = xv2.x; xv[2][1] = xv2.y; xv[2][2] = xv2.z; xv[2][3] = xv2.w;
        xv[3][0] = xv3.x; xv[3][1] = xv3.y; xv[3][2] = xv3.z; xv[3][3] = xv3.w;

#pragma unroll
        for (int a = 0; a < 4; ++a) {
            acc[a][0] += xv[a][0] * w0.x; acc[a][1] += xv[a][0] * w0.y;
            acc[a][2] += xv[a][0] * w0.z; acc[a][3] += xv[a][0] * w0.w;
            acc[a][0] += xv[a][1] * w1.x; acc[a][1] += xv[a][1] * w1.y;
            acc[a][2] += xv[a][1] * w1.z; acc[a][3] += xv[a][1] * w1.w;
            acc[a][0] += xv[a][2] * w2.x; acc[a][1] += xv[a][2] * w2.y;
            acc[a][2] += xv[a][2] * w2.z; acc[a][3] += xv[a][2] * w2.w;
            acc[a][0] += xv[a][3] * w3.x; acc[a][1] += xv[a][3] * w3.y;
            acc[a][2] += xv[a][3] * w3.z; acc[a][3] += xv[a][3] * w3.w;
        }
    }

    float* Pz = z ? P1 : P0;
#pragma unroll
    for (int a = 0; a < 4; ++a) {
        if (gn[a] < N_NODES)
            *((float4*)(Pz + (size_t)gn[a] * HIDDEN + kq)) =
                make_float4(acc[a][0], acc[a][1], acc[a][2], acc[a][3]);
    }
}

// H1[gid] = (P0[gid]+P1[gid])*ns; H1 aliases P0 at identical element offsets
__global__ void reduce1_kernel(const float* __restrict__ P0, const float* __restrict__ P1,
                               const float* __restrict__ norm_src, float* __restrict__ H1) {
    int gid = blockIdx.x * blockDim.x + threadIdx.x;
    if (gid < N_NODES * 4) {
        float4 a = ((const float4*)P0)[gid];
        float4 b = ((const float4*)P1)[gid];
        float ns = norm_src[gid >> 2];
        ((float4*)H1)[gid] = make_float4((a.x + b.x) * ns, (a.y + b.y) * ns,
                                         (a.z + b.z) * ns, (a.w + b.w) * ns);
    }
}

__global__ __launch_bounds__(256) void spmm1_kernel(
        const int* __restrict__ rp, const int* __restrict__ col,
        const float* __restrict__ H1, const float* __restrict__ norm_dst,
        const float* __restrict__ norm_src, const float* __restrict__ b1,
        float* __restrict__ H1b) {
    int tid = threadIdx.x;
    int node = blockIdx.x * 16 + (tid >> 4);
    int k = tid & 15;
    if (node >= N_NODES) return;
    int beg = rp[node], end = rp[node + 1];
    float acc = 0.f;
    int j = beg;
    for (; j + 3 < end; j += 4) {
        int s0 = col[j], s1 = col[j + 1], s2 = col[j + 2], s3 = col[j + 3];
        float v0 = H1[(size_t)s0 * HIDDEN + k];
        float v1 = H1[(size_t)s1 * HIDDEN + k];
        float v2 = H1[(size_t)s2 * HIDDEN + k];
        float v3 = H1[(size_t)s3 * HIDDEN + k];
        acc += v0 + v1 + v2 + v3;
    }
    for (; j < end; ++j) acc += H1[(size_t)col[j] * HIDDEN + k];
    float v = fmaxf(acc * norm_dst[node] + b1[k], 0.f) * norm_src[node];
    H1b[(size_t)node * HIDDEN + k] = v;
}

__global__ __launch_bounds__(256) void spmm2_final_kernel(
        const int* __restrict__ rp, const int* __restrict__ col,
        const float* __restrict__ H1b, const float* __restrict__ norm_dst,
        const float* __restrict__ W2, const float* __restrict__ b2,
        float* __restrict__ out) {
    __shared__ float w2s[HIDDEN * N_LABELS];
    int tid = threadIdx.x;
    ((float4*)w2s)[tid] = ((const float4*)W2)[tid];
    __syncthreads();

    int node = blockIdx.x * 16 + (tid >> 4);
    int k = tid & 15;
    if (node >= N_NODES) return;
    int beg = rp[node], end = rp[node + 1];
    float acc = 0.f;
    int j = beg;
    for (; j + 3 < end; j += 4) {
        int s0 = col[j], s1 = col[j + 1], s2 = col[j + 2], s3 = col[j + 3];
        float v0 = H1b[(size_t)s0 * HIDDEN + k];
        float v1 = H1b[(size_t)s1 * HIDDEN + k];
        float v2 = H1b[(size_t)s2 * HIDDEN + k];
        float v3 = H1b[(size_t)s3 * HIDDEN + k];
        acc += v0 + v1 + v2 + v3;
    }
    for (; j < end; ++j) acc += H1b[(size_t)col[j] * HIDDEN + k];
    acc *= norm_dst[node];

    float4 o = ((const float4*)b2)[k];
#pragma unroll
    for (int jj = 0; jj < HIDDEN; ++jj) {
        float hj = __shfl(acc, jj, 16);
        float4 w = *((const float4*)&w2s[jj * N_LABELS + 4 * k]);
        o.x += hj * w.x; o.y += hj * w.y; o.z += hj * w.z; o.w += hj * w.w;
    }
    ((float4*)out)[(size_t)node * 16 + k] = o;
}

extern "C" void kernel_launch(void* const* d_in, const int* in_sizes, int n_in,
                              void* d_out, int out_size, void* d_ws, size_t ws_size,
                              hipStream_t stream) {
    const float* X  = (const float*)d_in[0];
    const float* W1 = (const float*)d_in[1];
    const float* b1 = (const float*)d_in[2];
    const float* W2 = (const float*)d_in[3];
    const float* b2 = (const float*)d_in[4];
    const int* es   = (const int*)d_in[5];
    const int* ed   = (const int*)d_in[6];
    float* out = (float*)d_out;

    // ws (~26.8MB, <= 27.6MB proven in r3): norms | row_ptr | R1 | R2 | R3
    //  R1 (6.4M): srcb (scatter..srcdeg) -> P0 (proj1..reduce1) -> H1 (..spmm1)
    //  R2 (6.4M): Sdst/Ssrc/bs (count..srcdeg) -> P1 (proj1..reduce1) -> H1b
    //  R3 (12.8M): pairs (scatter..csr, converted IN PLACE) -> col (..end)
    char* ws = (char*)d_ws;
    float* norm_src = (float*)ws;  ws += (size_t)N_NODES * 4;
    float* norm_dst = (float*)ws;  ws += (size_t)N_NODES * 4;
    int*   row_ptr  = (int*)ws;    ws += 400016;
    char*  R1 = ws;                ws += (size_t)N_NODES * HIDDEN * 4;
    char*  R2 = ws;                ws += (size_t)N_NODES * HIDDEN * 4;
    char*  R3 = ws;

    unsigned char* srcb = (unsigned char*)R1;
    float* P0  = (float*)R1;
    float* H1  = (float*)R1;
    int*   Sdst = (int*)R2;
    int*   Ssrc = (int*)(R2 + 800768);
    int*   bs1  = (int*)(R2 + 1601536);
    int*   bs2  = (int*)(R2 + 1602560);
    float* P1   = (float*)R2;
    float* H1b  = (float*)R2;
    unsigned* pairs = (unsigned*)R3;
    int*   col  = (int*)R3;

    const int NPB = (N_NODES + MM_NODES - 1) / MM_NODES;  // 782

    count_kernel<<<NCB, 256, 0, stream>>>(es, ed, Ssrc, Sdst);
    scanA_kernel<<<SCAN_BLKS, 256, 0, stream>>>(Sdst, bs1);
    scanA_kernel<<<SCAN_BLKS, 256, 0, stream>>>(Ssrc, bs2);
    scanB_kernel<<<1, 256, 0, stream>>>(bs1);
    scanB_kernel<<<1, 256, 0, stream>>>(bs2);
    scanC_kernel<<<SCAN_BLKS, 256, 0, stream>>>(Sdst, bs1);
    scanC_kernel<<<SCAN_BLKS, 256, 0, stream>>>(Ssrc, bs2);
    scatter_kernel<<<NCB, 256, 0, stream>>>(es, ed, Ssrc, Sdst, pairs, srcb);
    csr_kernel<<<NBUCK, 256, 0, stream>>>(Sdst, pairs, row_ptr, norm_dst);
    srcdeg_kernel<<<NBUCK, 256, 0, stream>>>(Ssrc, srcb, norm_src);
    proj1_kernel<<<dim3(NPB, KSPLIT), 128, 0, stream>>>(X, W1, P0, P1);
    reduce1_kernel<<<(N_NODES * 4 + 255) / 256, 256, 0, stream>>>(P0, P1, norm_src, H1);
    spmm1_kernel<<<(N_NODES + 15) / 16, 256, 0, stream>>>(row_ptr, col, H1, norm_dst, norm_src, b1, H1b);
    spmm2_final_kernel<<<(N_NODES + 15) / 16, 256, 0, stream>>>(row_ptr, col, H1b, norm_dst, W2, b2, out);
}

// Round 4
// 598.765 us; speedup vs baseline: 1.0027x; 1.0027x over previous
//
#include <hip/hip_runtime.h>

#define N_NODES 100000
#define N_EDGES 3200000
#define F_IN 512
#define HIDDEN 16
#define N_LABELS 64

#define BW 128
#define NBUCK ((N_NODES + BW - 1) / BW)     // 782
#define NCB 256
#define SCAN_N (NBUCK * NCB)                // 200192
#define SCAN_BLKS ((SCAN_N + 1023) / 1024)  // 196
#define CAP 10240                           // LDS staging entries (40KB); buckets are 4096 +/- 64

__global__ __launch_bounds__(256) void count_kernel(
        const int* __restrict__ es, const int* __restrict__ ed,
        int* __restrict__ Msrc, int* __restrict__ Mdst) {
    __shared__ int h1[NBUCK], h2[NBUCK];
    const int tid = threadIdx.x, g = blockIdx.x;
    for (int i = tid; i < NBUCK; i += 256) { h1[i] = 0; h2[i] = 0; }
    __syncthreads();
    for (int i = g * 256 + tid; i < N_EDGES; i += NCB * 256) {
        atomicAdd(&h1[es[i] >> 7], 1);
        atomicAdd(&h2[ed[i] >> 7], 1);
    }
    __syncthreads();
    for (int i = tid; i < NBUCK; i += 256) {
        Msrc[i * NCB + g] = h1[i];
        Mdst[i * NCB + g] = h2[i];
    }
}

__global__ __launch_bounds__(256) void scanA_kernel(int* __restrict__ a, int* __restrict__ bsum) {
    __shared__ int s[256];
    const int tid = threadIdx.x;
    const int base = blockIdx.x * 1024 + tid * 4;
    int4 v = make_int4(0, 0, 0, 0);
    if (base + 3 < SCAN_N) v = *(const int4*)(a + base);
    else {
        if (base + 0 < SCAN_N) v.x = a[base + 0];
        if (base + 1 < SCAN_N) v.y = a[base + 1];
        if (base + 2 < SCAN_N) v.z = a[base + 2];
        if (base + 3 < SCAN_N) v.w = a[base + 3];
    }
    const int lsum = v.x + v.y + v.z + v.w;
    s[tid] = lsum;
    __syncthreads();
    for (int off = 1; off < 256; off <<= 1) {
        int t = (tid >= off) ? s[tid - off] : 0;
        __syncthreads();
        s[tid] += t;
        __syncthreads();
    }
    int e0 = s[tid] - lsum;
    int e1 = e0 + v.x, e2 = e1 + v.y, e3 = e2 + v.z;
    if (base + 3 < SCAN_N) *(int4*)(a + base) = make_int4(e0, e1, e2, e3);
    else {
        if (base + 0 < SCAN_N) a[base + 0] = e0;
        if (base + 1 < SCAN_N) a[base + 1] = e1;
        if (base + 2 < SCAN_N) a[base + 2] = e2;
        if (base + 3 < SCAN_N) a[base + 3] = e3;
    }
    if (tid == 255) bsum[blockIdx.x] = s[255];
}

__global__ void scanB_kernel(int* __restrict__ bsum) {
    __shared__ int s[256];
    const int tid = threadIdx.x;
    int v = (tid < SCAN_BLKS) ? bsum[tid] : 0;
    s[tid] = v;
    __syncthreads();
    for (int off = 1; off < 256; off <<= 1) {
        int t = (tid >= off) ? s[tid - off] : 0;
        __syncthreads();
        s[tid] += t;
        __syncthreads();
    }
    if (tid < SCAN_BLKS) bsum[tid] = s[tid] - v;
}

__global__ __launch_bounds__(256) void scanC_kernel(int* __restrict__ a, const int* __restrict__ bsum) {
    const int base = blockIdx.x * 1024 + threadIdx.x * 4;
    const int b = bsum[blockIdx.x];
    if (base + 3 < SCAN_N) {
        int4 v = *(int4*)(a + base);
        v.x += b; v.y += b; v.z += b; v.w += b;
        *(int4*)(a + base) = v;
    } else {
        for (int j = 0; j < 4; ++j) if (base + j < SCAN_N) a[base + j] += b;
    }
}

__global__ __launch_bounds__(256) void scatter_kernel(
        const int* __restrict__ es, const int* __restrict__ ed,
        const int* __restrict__ Ssrc, const int* __restrict__ Sdst,
        unsigned* __restrict__ pairs, unsigned char* __restrict__ srcb) {
    __shared__ int c1[NBUCK], c2[NBUCK];
    const int tid = threadIdx.x, g = blockIdx.x;
    for (int i = tid; i < NBUCK; i += 256) {
        c1[i] = Ssrc[i * NCB + g];
        c2[i] = Sdst[i * NCB + g];
    }
    __syncthreads();
    for (int i = g * 256 + tid; i < N_EDGES; i += NCB * 256) {
        int s = es[i], d = ed[i];
        int p2 = atomicAdd(&c2[d >> 7], 1);
        pairs[p2] = ((unsigned)(d & 127) << 17) | (unsigned)s;
        int p1 = atomicAdd(&c1[s >> 7], 1);
        srcb[p1] = (unsigned char)(s & 127);
    }
}

// Per-dst-bucket fine sort; converts pairs -> col IN PLACE.
__global__ __launch_bounds__(256) void csr_kernel(
        const int* __restrict__ Sdst, unsigned* __restrict__ pairs,
        int* __restrict__ row_ptr, float* __restrict__ norm_dst) {
    __shared__ unsigned buf[CAP];
    __shared__ int hist[BW], scn[BW], cur[BW];
    const int b = blockIdx.x, tid = threadIdx.x;
    const int base  = Sdst[b * NCB];
    const int nextb = (b == NBUCK - 1) ? N_EDGES : Sdst[(b + 1) * NCB];
    const int nb = nextb - base;
    const bool fits = (nb <= CAP);   // always true for this input (+96 sigma)
    if (tid < BW) hist[tid] = 0;
    __syncthreads();
    for (int i = tid; i < nb; i += 256) {
        unsigned pk = pairs[base + i];
        if (fits) buf[i] = pk;
        atomicAdd(&hist[pk >> 17], 1);
    }
    __syncthreads();
    if (tid < BW) scn[tid] = hist[tid];
    __syncthreads();
    for (int off = 1; off < BW; off <<= 1) {
        int t = 0;
        if (tid < BW && tid >= off) t = scn[tid - off];
        __syncthreads();
        if (tid < BW) scn[tid] += t;
        __syncthreads();
    }
    if (tid < BW) {
        int e = scn[tid] - hist[tid];
        cur[tid] = e;
        int node = b * BW + tid;
        if (node <= N_NODES) row_ptr[node] = base + e;
        if (node < N_NODES) norm_dst[node] = rsqrtf(fmaxf((float)hist[tid], 1.0f));
    }
    __syncthreads();
    if (fits) {
        for (int i = tid; i < nb; i += 256) {
            unsigned pk = buf[i];
            int pos = atomicAdd(&cur[pk >> 17], 1);
            pairs[base + pos] = pk & 0x1FFFFu;   // col value, within-bucket perm
        }
    } else {
        for (int i = tid; i < nb; i += 256)
            pairs[base + i] &= 0x1FFFFu;
    }
}

__global__ __launch_bounds__(256) void srcdeg_kernel(
        const int* __restrict__ Ssrc, const unsigned char* __restrict__ srcb,
        float* __restrict__ norm_src) {
    __shared__ int hist[BW];
    const int b = blockIdx.x, tid = threadIdx.x;
    const int base  = Ssrc[b * NCB];
    const int nextb = (b == NBUCK - 1) ? N_EDGES : Ssrc[(b + 1) * NCB];
    const int nb = nextb - base;
    if (tid < BW) hist[tid] = 0;
    __syncthreads();
    for (int i = tid; i < nb; i += 256)
        atomicAdd(&hist[srcb[base + i]], 1);
    __syncthreads();
    if (tid < BW) {
        int node = b * BW + tid;
        if (node < N_NODES) norm_src[node] = rsqrtf(fmaxf((float)hist[tid], 1.0f));
    }
}

// r8: r7's direct-global reads hit L1 set-aliasing (row stride 2048B pow2:
// 64 in-flight rows -> ~2 L1 sets -> no line reuse -> 4x HBM over-fetch =
// ~820MB = the observed ~107us). Fix: coalesced staging via
// __builtin_amdgcn_global_load_lds (no VGPR staging -> no r5 spill),
// DOUBLE-BUFFERED LDS, 2-phase: issue stage(c+1) BEFORE compute(c); the
// barrier's implicit vmcnt(0) lands after a full compute phase (T3-min).
// gload_lds writes linearly, so reads would 16-way bank-conflict; per rule
// #21: inverse-swizzled GLOBAL source + same-XOR on the LDS READ
// (cg ^= (row>>2)&7 -> 2-way = free). W1 half (16KB) staged once.
#define P1_ROWS 256
#define P1_CH 32
#define KSPLIT 2
#define KH (F_IN / KSPLIT)                  // 256
#define P1_CHUNKS (KH / P1_CH)              // 8
#define P1_BLKS ((N_NODES + P1_ROWS - 1) / P1_ROWS)  // 391

#define GLD16(gp, lp) __builtin_amdgcn_global_load_lds( \
    (const __attribute__((address_space(1))) unsigned int*)(gp), \
    (__attribute__((address_space(3))) unsigned int*)(lp), 16, 0, 0)

__global__ __launch_bounds__(256, 2) void proj1_kernel(
        const float* __restrict__ X, const float* __restrict__ W1,
        float* __restrict__ P0, float* __restrict__ P1) {
    __shared__ float xs[2][P1_ROWS * P1_CH];   // 2 x 32 KB
    __shared__ float w1c[KH * HIDDEN];         // 16 KB

    const int tid = threadIdx.x;
    const int node0 = blockIdx.x * P1_ROWS;
    const int z = blockIdx.y;

    // per-thread staging geometry: 8 calls x 64-lane waves cover 2048
    // 16B-units = 256 rows x 32 cols, LDS-linear. unit u = it*256+tid ->
    // row = u>>3 (it*32 + (tid>>3)), col-group cg = tid&7. 8 consecutive
    // lanes cover one row's full 128B (after XOR perm: same 128B) -> full
    // line utilization per instruction.
    const int srow0 = tid >> 3;           // + it*32
    const int scg   = tid & 7;
    const int wbase = tid & 192;          // wave-uniform lane base (16B units)

    // stage W1 z-half once (plain loads, drained by first barrier)
    for (int i = tid; i < KH * HIDDEN / 4; i += 256)
        ((float4*)w1c)[i] = ((const float4*)(W1 + (size_t)z * KH * HIDDEN))[i];

    // prologue: stage chunk 0 into buf 0
    {
        const float* Xc = X + (size_t)z * KH;   // chunk 0
#pragma unroll
        for (int it = 0; it < 8; ++it) {
            int row = srow0 + it * 32;
            int grow = node0 + row;
            if (grow > N_NODES - 1) grow = N_NODES - 1;   // clamp (write guarded)
            int cg = scg ^ ((row >> 2) & 7);              // inverse-swizzled source
            const float* gp = Xc + (size_t)grow * F_IN + cg * 4;
            float* lp = &xs[0][(size_t)(it * 256 + wbase) * 4];
            GLD16(gp, lp);
        }
    }
    __syncthreads();   // drains vmcnt+lgkmcnt: chunk0 + w1c ready

    const int rg = tid >> 2;          // rows rg*4 .. rg*4+3
    const int kq = (tid & 3) * 4;     // output quad

    float acc[4][4];
#pragma unroll
    for (int a = 0; a < 4; ++a)
#pragma unroll
        for (int b = 0; b < 4; ++b) acc[a][b] = 0.f;

    for (int cc = 0; cc < P1_CHUNKS; ++cc) {
        const int cur = cc & 1;

        // ---- issue next chunk's stage into the other buffer (async) ----
        if (cc + 1 < P1_CHUNKS) {
            const float* Xc = X + (size_t)z * KH + (size_t)(cc + 1) * P1_CH;
#pragma unroll
            for (int it = 0; it < 8; ++it) {
                int row = srow0 + it * 32;
                int grow = node0 + row;
                if (grow > N_NODES - 1) grow = N_NODES - 1;
                int cg = scg ^ ((row >> 2) & 7);
                const float* gp = Xc + (size_t)grow * F_IN + cg * 4;
                float* lp = &xs[cur ^ 1][(size_t)(it * 256 + wbase) * 4];
                GLD16(gp, lp);
            }
        }

        // ---- compute current chunk from LDS (overlaps in-flight loads) ----
        const float* xb = &xs[cur][0];
#pragma unroll
        for (int kk4 = 0; kk4 < 8; ++kk4) {
            float4 w0 = *((const float4*)&w1c[(cc * P1_CH + kk4 * 4 + 0) * HIDDEN + kq]);
            float4 w1 = *((const float4*)&w1c[(cc * P1_CH + kk4 * 4 + 1) * HIDDEN + kq]);
            float4 w2 = *((const float4*)&w1c[(cc * P1_CH + kk4 * 4 + 2) * HIDDEN + kq]);
            float4 w3 = *((const float4*)&w1c[(cc * P1_CH + kk4 * 4 + 3) * HIDDEN + kq]);
#pragma unroll
            for (int a = 0; a < 4; ++a) {
                int row = rg * 4 + a;
                int sw  = (row >> 2) & 7;                    // == rg&7
                float4 xv = *((const float4*)&xb[row * P1_CH + ((kk4 ^ sw) * 4)]);
                acc[a][0] += xv.x * w0.x; acc[a][1] += xv.x * w0.y;
                acc[a][2] += xv.x * w0.z; acc[a][3] += xv.x * w0.w;
                acc[a][0] += xv.y * w1.x; acc[a][1] += xv.y * w1.y;
                acc[a][2] += xv.y * w1.z; acc[a][3] += xv.y * w1.w;
                acc[a][0] += xv.z * w2.x; acc[a][1] += xv.z * w2.y;
                acc[a][2] += xv.z * w2.z; acc[a][3] += xv.z * w2.w;
                acc[a][0] += xv.w * w3.x; acc[a][1] += xv.w * w3.y;
                acc[a][2] += xv.w * w3.z; acc[a][3] += xv.w * w3.w;
            }
        }

        // barrier: (a) waits in-flight stage (implicit vmcnt(0) after a full
        // compute phase), (b) protects buf[cur] from next iter's overwrite
        __syncthreads();
    }

    float* Pz = z ? P1 : P0;
#pragma unroll
    for (int a = 0; a < 4; ++a) {
        int gn = node0 + rg * 4 + a;
        if (gn < N_NODES)
            *((float4*)(Pz + (size_t)gn * HIDDEN + kq)) =
                make_float4(acc[a][0], acc[a][1], acc[a][2], acc[a][3]);
    }
}

// H1[gid] = (P0[gid]+P1[gid])*ns; H1 aliases P0 at identical element offsets
__global__ void reduce1_kernel(const float* __restrict__ P0, const float* __restrict__ P1,
                               const float* __restrict__ norm_src, float* __restrict__ H1) {
    int gid = blockIdx.x * blockDim.x + threadIdx.x;
    if (gid < N_NODES * 4) {
        float4 a = ((const float4*)P0)[gid];
        float4 b = ((const float4*)P1)[gid];
        float ns = norm_src[gid >> 2];
        ((float4*)H1)[gid] = make_float4((a.x + b.x) * ns, (a.y + b.y) * ns,
                                         (a.z + b.z) * ns, (a.w + b.w) * ns);
    }
}

__global__ __launch_bounds__(256) void spmm1_kernel(
        const int* __restrict__ rp, const int* __restrict__ col,
        const float* __restrict__ H1, const float* __restrict__ norm_dst,
        const float* __restrict__ norm_src, const float* __restrict__ b1,
        float* __restrict__ H1b) {
    int tid = threadIdx.x;
    int node = blockIdx.x * 16 + (tid >> 4);
    int k = tid & 15;
    if (node >= N_NODES) return;
    int beg = rp[node], end = rp[node + 1];
    float acc = 0.f;
    int j = beg;
    for (; j + 3 < end; j += 4) {
        int s0 = col[j], s1 = col[j + 1], s2 = col[j + 2], s3 = col[j + 3];
        float v0 = H1[(size_t)s0 * HIDDEN + k];
        float v1 = H1[(size_t)s1 * HIDDEN + k];
        float v2 = H1[(size_t)s2 * HIDDEN + k];
        float v3 = H1[(size_t)s3 * HIDDEN + k];
        acc += v0 + v1 + v2 + v3;
    }
    for (; j < end; ++j) acc += H1[(size_t)col[j] * HIDDEN + k];
    float v = fmaxf(acc * norm_dst[node] + b1[k], 0.f) * norm_src[node];
    H1b[(size_t)node * HIDDEN + k] = v;
}

__global__ __launch_bounds__(256) void spmm2_final_kernel(
        const int* __restrict__ rp, const int* __restrict__ col,
        const float* __restrict__ H1b, const float* __restrict__ norm_dst,
        const float* __restrict__ W2, const float* __restrict__ b2,
        float* __restrict__ out) {
    __shared__ float w2s[HIDDEN * N_LABELS];
    int tid = threadIdx.x;
    ((float4*)w2s)[tid] = ((const float4*)W2)[tid];
    __syncthreads();

    int node = blockIdx.x * 16 + (tid >> 4);
    int k = tid & 15;
    if (node >= N_NODES) return;
    int beg = rp[node], end = rp[node + 1];
    float acc = 0.f;
    int j = beg;
    for (; j + 3 < end; j += 4) {
        int s0 = col[j], s1 = col[j + 1], s2 = col[j + 2], s3 = col[j + 3];
        float v0 = H1b[(size_t)s0 * HIDDEN + k];
        float v1 = H1b[(size_t)s1 * HIDDEN + k];
        float v2 = H1b[(size_t)s2 * HIDDEN + k];
        float v3 = H1b[(size_t)s3 * HIDDEN + k];
        acc += v0 + v1 + v2 + v3;
    }
    for (; j < end; ++j) acc += H1b[(size_t)col[j] * HIDDEN + k];
    acc *= norm_dst[node];

    float4 o = ((const float4*)b2)[k];
#pragma unroll
    for (int jj = 0; jj < HIDDEN; ++jj) {
        float hj = __shfl(acc, jj, 16);
        float4 w = *((const float4*)&w2s[jj * N_LABELS + 4 * k]);
        o.x += hj * w.x; o.y += hj * w.y; o.z += hj * w.z; o.w += hj * w.w;
    }
    ((float4*)out)[(size_t)node * 16 + k] = o;
}

extern "C" void kernel_launch(void* const* d_in, const int* in_sizes, int n_in,
                              void* d_out, int out_size, void* d_ws, size_t ws_size,
                              hipStream_t stream) {
    const float* X  = (const float*)d_in[0];
    const float* W1 = (const float*)d_in[1];
    const float* b1 = (const float*)d_in[2];
    const float* W2 = (const float*)d_in[3];
    const float* b2 = (const float*)d_in[4];
    const int* es   = (const int*)d_in[5];
    const int* ed   = (const int*)d_in[6];
    float* out = (float*)d_out;

    // ws (~26.8MB, <= 27.6MB proven in r3): norms | row_ptr | R1 | R2 | R3
    //  R1 (6.4M): srcb (scatter..srcdeg) -> P0 (proj1..reduce1) -> H1 (..spmm1)
    //  R2 (6.4M): Sdst/Ssrc/bs (count..srcdeg) -> P1 (proj1..reduce1) -> H1b
    //  R3 (12.8M): pairs (scatter..csr, converted IN PLACE) -> col (..end)
    char* ws = (char*)d_ws;
    float* norm_src = (float*)ws;  ws += (size_t)N_NODES * 4;
    float* norm_dst = (float*)ws;  ws += (size_t)N_NODES * 4;
    int*   row_ptr  = (int*)ws;    ws += 400016;
    char*  R1 = ws;                ws += (size_t)N_NODES * HIDDEN * 4;
    char*  R2 = ws;                ws += (size_t)N_NODES * HIDDEN * 4;
    char*  R3 = ws;

    unsigned char* srcb = (unsigned char*)R1;
    float* P0  = (float*)R1;
    float* H1  = (float*)R1;
    int*   Sdst = (int*)R2;
    int*   Ssrc = (int*)(R2 + 800768);
    int*   bs1  = (int*)(R2 + 1601536);
    int*   bs2  = (int*)(R2 + 1602560);
    float* P1   = (float*)R2;
    float* H1b  = (float*)R2;
    unsigned* pairs = (unsigned*)R3;
    int*   col  = (int*)R3;

    count_kernel<<<NCB, 256, 0, stream>>>(es, ed, Ssrc, Sdst);
    scanA_kernel<<<SCAN_BLKS, 256, 0, stream>>>(Sdst, bs1);
    scanA_kernel<<<SCAN_BLKS, 256, 0, stream>>>(Ssrc, bs2);
    scanB_kernel<<<1, 256, 0, stream>>>(bs1);
    scanB_kernel<<<1, 256, 0, stream>>>(bs2);
    scanC_kernel<<<SCAN_BLKS, 256, 0, stream>>>(Sdst, bs1);
    scanC_kernel<<<SCAN_BLKS, 256, 0, stream>>>(Ssrc, bs2);
    scatter_kernel<<<NCB, 256, 0, stream>>>(es, ed, Ssrc, Sdst, pairs, srcb);
    csr_kernel<<<NBUCK, 256, 0, stream>>>(Sdst, pairs, row_ptr, norm_dst);
    srcdeg_kernel<<<NBUCK, 256, 0, stream>>>(Ssrc, srcb, norm_src);
    proj1_kernel<<<dim3(P1_BLKS, KSPLIT), 256, 0, stream>>>(X, W1, P0, P1);
    reduce1_kernel<<<(N_NODES * 4 + 255) / 256, 256, 0, stream>>>(P0, P1, norm_src, H1);
    spmm1_kernel<<<(N_NODES + 15) / 16, 256, 0, stream>>>(row_ptr, col, H1, norm_dst, norm_src, b1, H1b);
    spmm2_final_kernel<<<(N_NODES + 15) / 16, 256, 0, stream>>>(row_ptr, col, H1b, norm_dst, W2, b2, out);
}